// Round 5
// baseline (568.676 us; speedup 1.0000x reference)
//
#include <hip/hip_runtime.h>

typedef __attribute__((ext_vector_type(8))) short bf16x8;
typedef __attribute__((ext_vector_type(4))) float f32x4;

#define CC 256
#define SS 1024
#define KK 4
#define XR 10
#define XC 34
#define KP 40   // xs stride (ushorts)

__device__ __forceinline__ unsigned int f2bf(float v) {
  unsigned int u = __float_as_uint(v);
  return (u + 0x7FFFu + ((u >> 16) & 1u)) >> 16;
}

// qk[c][n] = sum_d Wk[c, n*64+d] * q[n, d]
__global__ void qk_kernel(const float* __restrict__ Wk, const float* __restrict__ q,
                          float* __restrict__ qk) {
  int t = blockIdx.x * blockDim.x + threadIdx.x;
  if (t >= CC * 2) return;
  int c = t >> 1, n = t & 1;
  float s = 0.f;
  for (int d = 0; d < 64; ++d) s += Wk[c * 128 + n * 64 + d] * q[n * 64 + d];
  qk[c * 2 + n] = s;
}

// scores[b][n][s] = (x[b,s,:] . qk[:,n]) / 8   (one wave per pixel)
__global__ void scores_kernel(const float* __restrict__ x, const float* __restrict__ qk,
                              float* __restrict__ attn) {
  int wave = threadIdx.x >> 6, lane = threadIdx.x & 63;
  int pix = blockIdx.x * 4 + wave;
  int b = pix >> 10, s = pix & 1023;
  const float4 xv = *(const float4*)(x + (size_t)pix * CC + lane * 4);
  float d0 = 0.f, d1 = 0.f;
  const float* xp = (const float*)&xv;
#pragma unroll
  for (int j = 0; j < 4; ++j) {
    float xc = xp[j];
    d0 += xc * qk[(lane * 4 + j) * 2 + 0];
    d1 += xc * qk[(lane * 4 + j) * 2 + 1];
  }
#pragma unroll
  for (int m = 32; m >= 1; m >>= 1) {
    d0 += __shfl_xor(d0, m, 64);
    d1 += __shfl_xor(d1, m, 64);
  }
  if (lane == 0) {
    attn[((size_t)b * 2 + 0) * SS + s] = d0 * 0.125f;
    attn[((size_t)b * 2 + 1) * SS + s] = d1 * 0.125f;
  }
}

// block per batch: softmax both heads in-place + rowscale
__global__ void softmax_rs_kernel(float* __restrict__ attn, const float* __restrict__ alpha,
                                  float* __restrict__ rowscale) {
  __shared__ float red0[4], red1[4];
  int b = blockIdx.x, tid = threadIdx.x;
  float* p0 = attn + (size_t)b * 2048;
  float* p1 = p0 + 1024;
  float4 v0 = *(float4*)(p0 + tid * 4);
  float4 v1 = *(float4*)(p1 + tid * 4);
  float m0 = fmaxf(fmaxf(v0.x, v0.y), fmaxf(v0.z, v0.w));
  float m1 = fmaxf(fmaxf(v1.x, v1.y), fmaxf(v1.z, v1.w));
#pragma unroll
  for (int sh = 32; sh >= 1; sh >>= 1) {
    m0 = fmaxf(m0, __shfl_xor(m0, sh, 64));
    m1 = fmaxf(m1, __shfl_xor(m1, sh, 64));
  }
  if ((tid & 63) == 0) { red0[tid >> 6] = m0; red1[tid >> 6] = m1; }
  __syncthreads();
  m0 = fmaxf(fmaxf(red0[0], red0[1]), fmaxf(red0[2], red0[3]));
  m1 = fmaxf(fmaxf(red1[0], red1[1]), fmaxf(red1[2], red1[3]));
  float4 e0, e1;
  e0.x = expf(v0.x - m0); e0.y = expf(v0.y - m0); e0.z = expf(v0.z - m0); e0.w = expf(v0.w - m0);
  e1.x = expf(v1.x - m1); e1.y = expf(v1.y - m1); e1.z = expf(v1.z - m1); e1.w = expf(v1.w - m1);
  float s0 = e0.x + e0.y + e0.z + e0.w;
  float s1 = e1.x + e1.y + e1.z + e1.w;
#pragma unroll
  for (int sh = 32; sh >= 1; sh >>= 1) {
    s0 += __shfl_xor(s0, sh, 64);
    s1 += __shfl_xor(s1, sh, 64);
  }
  __syncthreads();
  if ((tid & 63) == 0) { red0[tid >> 6] = s0; red1[tid >> 6] = s1; }
  __syncthreads();
  s0 = red0[0] + red0[1] + red0[2] + red0[3];
  s1 = red1[0] + red1[1] + red1[2] + red1[3];
  float i0 = 1.f / s0, i1 = 1.f / s1;
  e0.x *= i0; e0.y *= i0; e0.z *= i0; e0.w *= i0;
  e1.x *= i1; e1.y *= i1; e1.z *= i1; e1.w *= i1;
  *(float4*)(p0 + tid * 4) = e0;
  *(float4*)(p1 + tid * 4) = e1;
  float al = alpha[0];
  float a = (al > 20.f) ? al : log1pf(expf(al));
  float k = 0.5f * 1024.f * a;
  float4 rs;
  rs.x = 1.f + (e0.x + e1.x) * k;
  rs.y = 1.f + (e0.y + e1.y) * k;
  rs.z = 1.f + (e0.z + e1.z) * k;
  rs.w = 1.f + (e0.w + e1.w) * k;
  *(float4*)(rowscale + (size_t)b * 1024 + tid * 4) = rs;
}

// partial xa over 64-s chunks: xa_part[b][ch][n][c]
__global__ void xa_part_kernel(const float* __restrict__ x, const float* __restrict__ attn,
                               float* __restrict__ xa_part) {
  int ch = blockIdx.x, b = blockIdx.y, c = threadIdx.x;
  int s0 = ch * 64;
  const float* a0 = attn + (size_t)b * 2048 + s0;
  const float* a1 = a0 + 1024;
  const float* xb = x + ((size_t)b * 1024 + s0) * CC + c;
  float acc0 = 0.f, acc1 = 0.f;
  for (int i = 0; i < 64; ++i) {
    float xv = xb[(size_t)i * CC];
    acc0 += a0[i] * xv;
    acc1 += a1[i] * xv;
  }
  float* o = xa_part + ((size_t)b * 16 + ch) * 512;
  o[c] = acc0;
  o[256 + c] = acc1;
}

// reduce xa_part -> pooled -> logits -> top-2 routing
__global__ void route_kernel(const float* __restrict__ xa_part, const float* __restrict__ Wv,
                             const float* __restrict__ Wmlp, float* __restrict__ allowed,
                             int* __restrict__ selE, float* __restrict__ selW, int step) {
  __shared__ float xs[512];
  __shared__ float pooled[128];
  __shared__ float lg[4];
  int b = blockIdx.x, tid = threadIdx.x;
#pragma unroll
  for (int i = 0; i < 2; ++i) {
    int id = tid + i * 256;
    float s = 0.f;
    for (int ch = 0; ch < 16; ++ch) s += xa_part[((size_t)b * 16 + ch) * 512 + id];
    xs[id] = s;
  }
  __syncthreads();
  if (tid < 128) {
    int n = tid >> 6;
    float s = 0.f;
    const float* xr = xs + n * 256;
    for (int c = 0; c < 256; ++c) s += xr[c] * Wv[(size_t)c * 128 + tid];
    pooled[tid] = s;
  }
  __syncthreads();
  if (tid < 4) {
    float s = 0.f;
    for (int d = 0; d < 128; ++d) s += pooled[d] * Wmlp[d * 4 + tid];
    lg[tid] = s;
  }
  __syncthreads();
  if (tid == 0) {
    float al[KK];
    if (step == 0) { for (int k = 0; k < KK; ++k) al[k] = 1.f; }
    else           { for (int k = 0; k < KK; ++k) al[k] = allowed[b * KK + k]; }
    float ml[KK];
    for (int k = 0; k < KK; ++k)
      ml[k] = (al[k] > 0.5f) ? lg[k] * (1.f / 1.5f) : (-1e9f) * (1.f / 1.5f);
    float m = ml[0];
    for (int k = 1; k < KK; ++k) m = fmaxf(m, ml[k]);
    float e[KK], ssum = 0.f;
    for (int k = 0; k < KK; ++k) { e[k] = expf(ml[k] - m); ssum += e[k]; }
    float w[KK];
    for (int k = 0; k < KK; ++k) w[k] = e[k] / ssum;
    int i0 = 0;
    for (int k = 1; k < KK; ++k) if (w[k] > w[i0]) i0 = k;
    int i1 = -1;
    for (int k = 0; k < KK; ++k) {
      if (k == i0) continue;
      if (i1 < 0 || w[k] > w[i1]) i1 = k;
    }
    float denom = w[i0] + w[i1] + 1e-9f;
    selE[b * 2 + 0] = i0;
    selE[b * 2 + 1] = i1;
    selW[b * 2 + 0] = w[i0] / denom;
    selW[b * 2 + 1] = w[i1] / denom;
    if (i0 != KK - 1) al[i0] = fminf(fmaxf(al[i0] - 1.f, 0.f), 1.f);
    al[KK - 1] = fmaxf(al[KK - 1], 1.f);
    for (int k = 0; k < KK; ++k) allowed[b * KK + k] = al[k];
  }
}

// Per-batch combined expert weights (exact f32 combine), split to bf16 hi/lo,
// transposed layout: Wc_{h,l}[(b*72 + tap*8 + kc)*8192 + co*32 + ki]
__global__ void combine_w_kernel(const float* __restrict__ We,
                                 const int* __restrict__ selE, const float* __restrict__ selW,
                                 unsigned short* __restrict__ Wc_h,
                                 unsigned short* __restrict__ Wc_l) {
  int tile = blockIdx.x;  // 0..71 = tap*8+kc
  int b = blockIdx.y;
  int tap = tile >> 3, kc = tile & 7;
  int co = threadIdx.x;
  int e0 = selE[b * 2], e1 = selE[b * 2 + 1];
  float w0 = selW[b * 2], w1 = selW[b * 2 + 1];
  __shared__ float ts[32][257];
  const float* s0 = We + (size_t)(e0 * 9 + tap) * 65536 + (size_t)(kc * 32) * 256 + co;
  const float* s1 = We + (size_t)(e1 * 9 + tap) * 65536 + (size_t)(kc * 32) * 256 + co;
  for (int ci = 0; ci < 32; ++ci)
    ts[ci][co] = w0 * s0[(size_t)ci * 256] + w1 * s1[(size_t)ci * 256];
  __syncthreads();
  __align__(16) unsigned short hh[32];
  __align__(16) unsigned short ll[32];
#pragma unroll
  for (int ki = 0; ki < 32; ++ki) {
    float v = ts[ki][co];
    unsigned int h = f2bf(v);
    unsigned int l = f2bf(v - __uint_as_float(h << 16));
    hh[ki] = (unsigned short)h;
    ll[ki] = (unsigned short)l;
  }
  size_t base = ((size_t)b * 72 + tile) * 8192 + (size_t)co * 32;
#pragma unroll
  for (int j = 0; j < 4; ++j) {
    *(uint4*)(Wc_h + base + j * 8) = *(const uint4*)(hh + j * 8);
    *(uint4*)(Wc_l + base + j * 8) = *(const uint4*)(ll + j * 8);
  }
}

// MFMA implicit-GEMM conv, precombined weights. Block = 256 thr (4 waves, wm
// 0..3), M=256 pixels (8 rows + halo), N=64 cos. B-fragments load DIRECTLY
// from global (no LDS, register double-buffer); A (x hi/lo) staged in LDS
// once per kc. 3 split-bf16 terms, f32 accum. 2 barriers per kc.
__global__ __launch_bounds__(256, 2) void conv_kernel(
    const float* __restrict__ xin, const float* __restrict__ rowscale,
    const unsigned short* __restrict__ Wc_h, const unsigned short* __restrict__ Wc_l,
    const float* __restrict__ be,
    const int* __restrict__ selE, const float* __restrict__ selW,
    float* __restrict__ out) {
  __shared__ unsigned short xs_h[XR * XC * KP];
  __shared__ unsigned short xs_l[XR * XC * KP];
  __shared__ float rs_lds[XR * XC];

  int bid = blockIdx.x;
  // XCD swizzle: group g=(b*4+nt) -> xcd g%8; 4 mt-blocks of a group co-XCD.
  int g = (bid >> 5) * 8 + (bid & 7);
  int mt = (bid >> 3) & 3;
  int b = g >> 2, nt = g & 3;
  int h0 = mt * 8;
  int tid = threadIdx.x;
  int lane = tid & 63, wm = tid >> 6;
  int l15 = lane & 15, kl = lane >> 4;

  int e0 = selE[b * 2], e1 = selE[b * 2 + 1];
  float w0 = selW[b * 2], w1 = selW[b * 2 + 1];

  for (int i = tid; i < XR * XC; i += 256) {
    int r = i / XC, c = i - r * XC;
    int gr = h0 - 1 + r, gc = c - 1;
    float v = 0.f;
    if (gr >= 0 && gr < 32 && gc >= 0 && gc < 32)
      v = rowscale[(size_t)b * 1024 + gr * 32 + gc];
    rs_lds[i] = v;
  }

  int prow[4], pcb[4];
#pragma unroll
  for (int mf = 0; mf < 4; ++mf) {
    int pm = wm * 64 + mf * 16;
    prow[mf] = pm >> 5;
    pcb[mf] = pm & 31;
  }
  int loff[4];
#pragma unroll
  for (int nf = 0; nf < 4; ++nf) loff[nf] = (nf * 16 + l15) * 32 + kl * 8;

  const unsigned short* WH = Wc_h + (size_t)b * 72 * 8192 + nt * 2048;
  const unsigned short* WL = Wc_l + (size_t)b * 72 * 8192 + nt * 2048;

  float bias[4];
#pragma unroll
  for (int nf = 0; nf < 4; ++nf) {
    int con = nt * 64 + nf * 16 + l15;
    bias[nf] = w0 * be[e0 * 256 + con] + w1 * be[e1 * 256 + con];
  }

  f32x4 acc[4][4];
#pragma unroll
  for (int mf = 0; mf < 4; ++mf)
#pragma unroll
    for (int nf = 0; nf < 4; ++nf) acc[mf][nf] = (f32x4){0.f, 0.f, 0.f, 0.f};

  auto stage_x = [&](int kc) {
    for (int idx = tid; idx < XR * XC * 8; idx += 256) {
      int ki4 = idx & 7, cell = idx >> 3;
      int r = cell / XC, c = cell - r * XC;
      int gr = h0 - 1 + r, gc = c - 1;
      float4 v = make_float4(0.f, 0.f, 0.f, 0.f);
      if (gr >= 0 && gr < 32 && gc >= 0 && gc < 32)
        v = *(const float4*)(xin + (((size_t)b * 32 + gr) * 32 + gc) * 256 + kc * 32 + ki4 * 4);
      float sc = rs_lds[cell];
      float x0 = v.x * sc, x1 = v.y * sc, x2 = v.z * sc, x3 = v.w * sc;
      unsigned int h0b = f2bf(x0), h1b = f2bf(x1), h2b = f2bf(x2), h3b = f2bf(x3);
      unsigned int l0b = f2bf(x0 - __uint_as_float(h0b << 16));
      unsigned int l1b = f2bf(x1 - __uint_as_float(h1b << 16));
      unsigned int l2b = f2bf(x2 - __uint_as_float(h2b << 16));
      unsigned int l3b = f2bf(x3 - __uint_as_float(h3b << 16));
      uint2 hw = make_uint2(h0b | (h1b << 16), h2b | (h3b << 16));
      uint2 lw2 = make_uint2(l0b | (l1b << 16), l2b | (l3b << 16));
      *(uint2*)(xs_h + cell * KP + ki4 * 4) = hw;
      *(uint2*)(xs_l + cell * KP + ki4 * 4) = lw2;
    }
  };

  // preload B fragments for (tap=0, kc=0): tile offset 0
  bf16x8 cbh[4], cbl[4];
#pragma unroll
  for (int nf = 0; nf < 4; ++nf) {
    cbh[nf] = *(const bf16x8*)(WH + loff[nf]);
    cbl[nf] = *(const bf16x8*)(WL + loff[nf]);
  }

  __syncthreads();  // rs_lds ready
#pragma unroll 1
  for (int kc = 0; kc < 8; ++kc) {
    stage_x(kc);
    __syncthreads();
#pragma unroll
    for (int tap = 0; tap < 9; ++tap) {
      int ntap = tap + 1, nkc = kc;
      if (ntap == 9) { ntap = 0; nkc = kc + 1; }
      bool pf = (nkc < 8);
      bf16x8 nbh[4], nbl[4];
      if (pf) {
        size_t toff = (size_t)(ntap * 8 + nkc) * 8192;
#pragma unroll
        for (int nf = 0; nf < 4; ++nf) {
          nbh[nf] = *(const bf16x8*)(WH + toff + loff[nf]);
          nbl[nf] = *(const bf16x8*)(WL + toff + loff[nf]);
        }
      }

      int dy = tap / 3, dx = tap - dy * 3;
      int aoff[4];
#pragma unroll
      for (int mf = 0; mf < 4; ++mf)
        aoff[mf] = ((prow[mf] + dy) * XC + pcb[mf] + l15 + dx) * KP + kl * 8;

      bf16x8 afh[4];
#pragma unroll
      for (int mf = 0; mf < 4; ++mf) afh[mf] = *(const bf16x8*)(xs_h + aoff[mf]);
#pragma unroll
      for (int mf = 0; mf < 4; ++mf)
#pragma unroll
        for (int nf = 0; nf < 4; ++nf)
          acc[mf][nf] = __builtin_amdgcn_mfma_f32_16x16x32_bf16(afh[mf], cbh[nf], acc[mf][nf], 0, 0, 0);
#pragma unroll
      for (int mf = 0; mf < 4; ++mf)
#pragma unroll
        for (int nf = 0; nf < 4; ++nf)
          acc[mf][nf] = __builtin_amdgcn_mfma_f32_16x16x32_bf16(afh[mf], cbl[nf], acc[mf][nf], 0, 0, 0);
      bf16x8 afl[4];
#pragma unroll
      for (int mf = 0; mf < 4; ++mf) afl[mf] = *(const bf16x8*)(xs_l + aoff[mf]);
#pragma unroll
      for (int mf = 0; mf < 4; ++mf)
#pragma unroll
        for (int nf = 0; nf < 4; ++nf)
          acc[mf][nf] = __builtin_amdgcn_mfma_f32_16x16x32_bf16(afl[mf], cbh[nf], acc[mf][nf], 0, 0, 0);

      if (pf) {
#pragma unroll
        for (int nf = 0; nf < 4; ++nf) { cbh[nf] = nbh[nf]; cbl[nf] = nbl[nf]; }
      }
    }
    __syncthreads();  // xs reads done before next stage overwrites
  }

#pragma unroll
  for (int mf = 0; mf < 4; ++mf) {
    size_t rowbase = ((size_t)b * 32 + h0 + prow[mf]) * 32;
#pragma unroll
    for (int nf = 0; nf < 4; ++nf) {
      int co = nt * 64 + nf * 16 + l15;
#pragma unroll
      for (int r = 0; r < 4; ++r) {
        int col = pcb[mf] + kl * 4 + r;
        out[(rowbase + col) * 256 + co] = acc[mf][nf][r] + bias[nf];
      }
    }
  }
}

extern "C" void kernel_launch(void* const* d_in, const int* in_sizes, int n_in,
                              void* d_out, int out_size, void* d_ws, size_t ws_size,
                              hipStream_t stream) {
  const float* x_in  = (const float*)d_in[0];
  const float* q     = (const float*)d_in[1];
  const float* Wk    = (const float*)d_in[2];
  const float* Wv    = (const float*)d_in[3];
  const float* Wmlp  = (const float*)d_in[4];
  const float* alpha = (const float*)d_in[5];
  const float* We    = (const float*)d_in[6];
  const float* be    = (const float*)d_in[7];
  float* out = (float*)d_out;
  float* ws = (float*)d_ws;

  float* qk       = ws;                 // 512
  float* attn     = qk + 512;           // 65536
  float* rowscale = attn + 65536;       // 32768
  float* xa_part  = rowscale + 32768;   // 262144
  float* allowed  = xa_part + 262144;   // 128
  float* selW     = allowed + 128;      // 64
  int*   selE     = (int*)(selW + 64);  // 64
  float* xbuf     = selW + 128;         // 8388608 floats
  unsigned short* Wc_h = (unsigned short*)(xbuf + 8388608);  // 18,874,368 ushorts
  unsigned short* Wc_l = Wc_h + (size_t)32 * 72 * 8192;      // 18,874,368 ushorts

  qk_kernel<<<2, 256, 0, stream>>>(Wk, q, qk);

  const float* step_in[3] = {x_in, out, xbuf};
  float* step_out[3] = {out, xbuf, out};

  for (int t = 0; t < 3; ++t) {
    const float* xc = step_in[t];
    scores_kernel<<<8192, 256, 0, stream>>>(xc, qk, attn);
    softmax_rs_kernel<<<32, 256, 0, stream>>>(attn, alpha, rowscale);
    xa_part_kernel<<<dim3(16, 32), 256, 0, stream>>>(xc, attn, xa_part);
    route_kernel<<<32, 256, 0, stream>>>(xa_part, Wv, Wmlp, allowed, selE, selW, t);
    combine_w_kernel<<<dim3(72, 32), 256, 0, stream>>>(We, selE, selW, Wc_h, Wc_l);
    conv_kernel<<<512, 256, 0, stream>>>(xc, rowscale, Wc_h, Wc_l, be, selE, selW, step_out[t]);
  }
}

// Round 6
// 499.104 us; speedup vs baseline: 1.1394x; 1.1394x over previous
//
#include <hip/hip_runtime.h>

typedef __attribute__((ext_vector_type(8))) short bf16x8;
typedef __attribute__((ext_vector_type(4))) float f32x4;

#define CC 256
#define SS 1024
#define KK 4
#define XR 10
#define XC 34
#define KP 40   // LDS stride (ushorts) for both xs and Bs rows

__device__ __forceinline__ unsigned int f2bf(float v) {
  unsigned int u = __float_as_uint(v);
  return (u + 0x7FFFu + ((u >> 16) & 1u)) >> 16;
}

// qk[c][n] = sum_d Wk[c, n*64+d] * q[n, d]
__global__ void qk_kernel(const float* __restrict__ Wk, const float* __restrict__ q,
                          float* __restrict__ qk) {
  int t = blockIdx.x * blockDim.x + threadIdx.x;
  if (t >= CC * 2) return;
  int c = t >> 1, n = t & 1;
  float s = 0.f;
  for (int d = 0; d < 64; ++d) s += Wk[c * 128 + n * 64 + d] * q[n * 64 + d];
  qk[c * 2 + n] = s;
}

// scores[b][n][s] = (x[b,s,:] . qk[:,n]) / 8   (one wave per pixel)
__global__ void scores_kernel(const float* __restrict__ x, const float* __restrict__ qk,
                              float* __restrict__ attn) {
  int wave = threadIdx.x >> 6, lane = threadIdx.x & 63;
  int pix = blockIdx.x * 4 + wave;
  int b = pix >> 10, s = pix & 1023;
  const float4 xv = *(const float4*)(x + (size_t)pix * CC + lane * 4);
  float d0 = 0.f, d1 = 0.f;
  const float* xp = (const float*)&xv;
#pragma unroll
  for (int j = 0; j < 4; ++j) {
    float xc = xp[j];
    d0 += xc * qk[(lane * 4 + j) * 2 + 0];
    d1 += xc * qk[(lane * 4 + j) * 2 + 1];
  }
#pragma unroll
  for (int m = 32; m >= 1; m >>= 1) {
    d0 += __shfl_xor(d0, m, 64);
    d1 += __shfl_xor(d1, m, 64);
  }
  if (lane == 0) {
    attn[((size_t)b * 2 + 0) * SS + s] = d0 * 0.125f;
    attn[((size_t)b * 2 + 1) * SS + s] = d1 * 0.125f;
  }
}

// block per batch: softmax both heads in-place + rowscale
__global__ void softmax_rs_kernel(float* __restrict__ attn, const float* __restrict__ alpha,
                                  float* __restrict__ rowscale) {
  __shared__ float red0[4], red1[4];
  int b = blockIdx.x, tid = threadIdx.x;
  float* p0 = attn + (size_t)b * 2048;
  float* p1 = p0 + 1024;
  float4 v0 = *(float4*)(p0 + tid * 4);
  float4 v1 = *(float4*)(p1 + tid * 4);
  float m0 = fmaxf(fmaxf(v0.x, v0.y), fmaxf(v0.z, v0.w));
  float m1 = fmaxf(fmaxf(v1.x, v1.y), fmaxf(v1.z, v1.w));
#pragma unroll
  for (int sh = 32; sh >= 1; sh >>= 1) {
    m0 = fmaxf(m0, __shfl_xor(m0, sh, 64));
    m1 = fmaxf(m1, __shfl_xor(m1, sh, 64));
  }
  if ((tid & 63) == 0) { red0[tid >> 6] = m0; red1[tid >> 6] = m1; }
  __syncthreads();
  m0 = fmaxf(fmaxf(red0[0], red0[1]), fmaxf(red0[2], red0[3]));
  m1 = fmaxf(fmaxf(red1[0], red1[1]), fmaxf(red1[2], red1[3]));
  float4 e0, e1;
  e0.x = expf(v0.x - m0); e0.y = expf(v0.y - m0); e0.z = expf(v0.z - m0); e0.w = expf(v0.w - m0);
  e1.x = expf(v1.x - m1); e1.y = expf(v1.y - m1); e1.z = expf(v1.z - m1); e1.w = expf(v1.w - m1);
  float s0 = e0.x + e0.y + e0.z + e0.w;
  float s1 = e1.x + e1.y + e1.z + e1.w;
#pragma unroll
  for (int sh = 32; sh >= 1; sh >>= 1) {
    s0 += __shfl_xor(s0, sh, 64);
    s1 += __shfl_xor(s1, sh, 64);
  }
  __syncthreads();
  if ((tid & 63) == 0) { red0[tid >> 6] = s0; red1[tid >> 6] = s1; }
  __syncthreads();
  s0 = red0[0] + red0[1] + red0[2] + red0[3];
  s1 = red1[0] + red1[1] + red1[2] + red1[3];
  float i0 = 1.f / s0, i1 = 1.f / s1;
  e0.x *= i0; e0.y *= i0; e0.z *= i0; e0.w *= i0;
  e1.x *= i1; e1.y *= i1; e1.z *= i1; e1.w *= i1;
  *(float4*)(p0 + tid * 4) = e0;
  *(float4*)(p1 + tid * 4) = e1;
  float al = alpha[0];
  float a = (al > 20.f) ? al : log1pf(expf(al));
  float k = 0.5f * 1024.f * a;
  float4 rs;
  rs.x = 1.f + (e0.x + e1.x) * k;
  rs.y = 1.f + (e0.y + e1.y) * k;
  rs.z = 1.f + (e0.z + e1.z) * k;
  rs.w = 1.f + (e0.w + e1.w) * k;
  *(float4*)(rowscale + (size_t)b * 1024 + tid * 4) = rs;
}

// partial xa over 64-s chunks: xa_part[b][ch][n][c]
__global__ void xa_part_kernel(const float* __restrict__ x, const float* __restrict__ attn,
                               float* __restrict__ xa_part) {
  int ch = blockIdx.x, b = blockIdx.y, c = threadIdx.x;
  int s0 = ch * 64;
  const float* a0 = attn + (size_t)b * 2048 + s0;
  const float* a1 = a0 + 1024;
  const float* xb = x + ((size_t)b * 1024 + s0) * CC + c;
  float acc0 = 0.f, acc1 = 0.f;
  for (int i = 0; i < 64; ++i) {
    float xv = xb[(size_t)i * CC];
    acc0 += a0[i] * xv;
    acc1 += a1[i] * xv;
  }
  float* o = xa_part + ((size_t)b * 16 + ch) * 512;
  o[c] = acc0;
  o[256 + c] = acc1;
}

// reduce xa_part -> pooled -> logits -> top-2 routing
__global__ void route_kernel(const float* __restrict__ xa_part, const float* __restrict__ Wv,
                             const float* __restrict__ Wmlp, float* __restrict__ allowed,
                             int* __restrict__ selE, float* __restrict__ selW, int step) {
  __shared__ float xs[512];
  __shared__ float pooled[128];
  __shared__ float lg[4];
  int b = blockIdx.x, tid = threadIdx.x;
#pragma unroll
  for (int i = 0; i < 2; ++i) {
    int id = tid + i * 256;
    float s = 0.f;
    for (int ch = 0; ch < 16; ++ch) s += xa_part[((size_t)b * 16 + ch) * 512 + id];
    xs[id] = s;
  }
  __syncthreads();
  if (tid < 128) {
    int n = tid >> 6;
    float s = 0.f;
    const float* xr = xs + n * 256;
    for (int c = 0; c < 256; ++c) s += xr[c] * Wv[(size_t)c * 128 + tid];
    pooled[tid] = s;
  }
  __syncthreads();
  if (tid < 4) {
    float s = 0.f;
    for (int d = 0; d < 128; ++d) s += pooled[d] * Wmlp[d * 4 + tid];
    lg[tid] = s;
  }
  __syncthreads();
  if (tid == 0) {
    float al[KK];
    if (step == 0) { for (int k = 0; k < KK; ++k) al[k] = 1.f; }
    else           { for (int k = 0; k < KK; ++k) al[k] = allowed[b * KK + k]; }
    float ml[KK];
    for (int k = 0; k < KK; ++k)
      ml[k] = (al[k] > 0.5f) ? lg[k] * (1.f / 1.5f) : (-1e9f) * (1.f / 1.5f);
    float m = ml[0];
    for (int k = 1; k < KK; ++k) m = fmaxf(m, ml[k]);
    float e[KK], ssum = 0.f;
    for (int k = 0; k < KK; ++k) { e[k] = expf(ml[k] - m); ssum += e[k]; }
    float w[KK];
    for (int k = 0; k < KK; ++k) w[k] = e[k] / ssum;
    int i0 = 0;
    for (int k = 1; k < KK; ++k) if (w[k] > w[i0]) i0 = k;
    int i1 = -1;
    for (int k = 0; k < KK; ++k) {
      if (k == i0) continue;
      if (i1 < 0 || w[k] > w[i1]) i1 = k;
    }
    float denom = w[i0] + w[i1] + 1e-9f;
    selE[b * 2 + 0] = i0;
    selE[b * 2 + 1] = i1;
    selW[b * 2 + 0] = w[i0] / denom;
    selW[b * 2 + 1] = w[i1] / denom;
    if (i0 != KK - 1) al[i0] = fminf(fmaxf(al[i0] - 1.f, 0.f), 1.f);
    al[KK - 1] = fmaxf(al[KK - 1], 1.f);
    for (int k = 0; k < KK; ++k) allowed[b * KK + k] = al[k];
  }
}

// Per-batch combined expert weights (exact f32 combine), split to bf16 hi/lo,
// transposed packed layout: Wc_{h,l}[(b*72 + tile)*8192 + co*32 + ki]
__global__ void combine_w_kernel(const float* __restrict__ We,
                                 const int* __restrict__ selE, const float* __restrict__ selW,
                                 unsigned short* __restrict__ Wc_h,
                                 unsigned short* __restrict__ Wc_l) {
  int tile = blockIdx.x;  // 0..71 = tap*8+kc
  int b = blockIdx.y;
  int tap = tile >> 3, kc = tile & 7;
  int co = threadIdx.x;
  int e0 = selE[b * 2], e1 = selE[b * 2 + 1];
  float w0 = selW[b * 2], w1 = selW[b * 2 + 1];
  __shared__ float ts[32][257];
  const float* s0 = We + (size_t)(e0 * 9 + tap) * 65536 + (size_t)(kc * 32) * 256 + co;
  const float* s1 = We + (size_t)(e1 * 9 + tap) * 65536 + (size_t)(kc * 32) * 256 + co;
  for (int ci = 0; ci < 32; ++ci)
    ts[ci][co] = w0 * s0[(size_t)ci * 256] + w1 * s1[(size_t)ci * 256];
  __syncthreads();
  __align__(16) unsigned short hh[32];
  __align__(16) unsigned short ll[32];
#pragma unroll
  for (int ki = 0; ki < 32; ++ki) {
    float v = ts[ki][co];
    unsigned int h = f2bf(v);
    unsigned int l = f2bf(v - __uint_as_float(h << 16));
    hh[ki] = (unsigned short)h;
    ll[ki] = (unsigned short)l;
  }
  size_t base = ((size_t)b * 72 + tile) * 8192 + (size_t)co * 32;
#pragma unroll
  for (int j = 0; j < 4; ++j) {
    *(uint4*)(Wc_h + base + j * 8) = *(const uint4*)(hh + j * 8);
    *(uint4*)(Wc_l + base + j * 8) = *(const uint4*)(ll + j * 8);
  }
}

// MFMA implicit-GEMM conv. Block = 512 thr (8 waves, 4m x 2n), tile
// M=256 pixels (8 image rows + halo), N=128 cos; wave tile 64x64
// (mf=nf=4 of 16x16x32). B in LDS (padded stride, double-buffered,
// reg-staged with early-issue/late-write). 3 split-bf16 terms, f32 accum.
// 1 barrier per tap. Grid 256 = 1 block/CU; XCD swizzle groups the 8
// blocks of a batch on one XCD.
__global__ __launch_bounds__(512, 2) void conv_kernel(
    const float* __restrict__ xin, const float* __restrict__ rowscale,
    const unsigned short* __restrict__ Wc_h, const unsigned short* __restrict__ Wc_l,
    const float* __restrict__ be,
    const int* __restrict__ selE, const float* __restrict__ selW,
    float* __restrict__ out) {
  __shared__ unsigned short xs_h[XR * XC * KP];
  __shared__ unsigned short xs_l[XR * XC * KP];
  __shared__ unsigned short Bs[2][2][128 * KP];
  __shared__ float rs_lds[XR * XC];

  int bid = blockIdx.x;
  int xcd = bid & 7, i = bid >> 3;
  int b = xcd * 4 + (i >> 3);
  int sub = i & 7;
  int mt = sub >> 1, nt = sub & 1;
  int h0 = mt * 8;
  int tid = threadIdx.x;
  int lane = tid & 63, wid = tid >> 6;
  int wm = wid >> 1, wn = wid & 1;
  int l15 = lane & 15, kl = lane >> 4;

  int e0 = selE[b * 2], e1 = selE[b * 2 + 1];
  float w0 = selW[b * 2], w1 = selW[b * 2 + 1];

  for (int idx = tid; idx < XR * XC; idx += 512) {
    int r = idx / XC, c = idx - r * XC;
    int gr = h0 - 1 + r, gc = c - 1;
    float v = 0.f;
    if (gr >= 0 && gr < 32 && gc >= 0 && gc < 32)
      v = rowscale[(size_t)b * 1024 + gr * 32 + gc];
    rs_lds[idx] = v;
  }

  int prow[4], pcb[4];
#pragma unroll
  for (int mf = 0; mf < 4; ++mf) {
    int pm = wm * 64 + mf * 16;
    prow[mf] = pm >> 5;
    pcb[mf] = pm & 31;
  }
  int boff[4];
#pragma unroll
  for (int nf = 0; nf < 4; ++nf) boff[nf] = (wn * 64 + nf * 16 + l15) * KP + kl * 8;

  float bias[4];
#pragma unroll
  for (int nf = 0; nf < 4; ++nf) {
    int con = nt * 128 + wn * 64 + nf * 16 + l15;
    bias[nf] = w0 * be[e0 * 256 + con] + w1 * be[e1 * 256 + con];
  }

  f32x4 acc[4][4];
#pragma unroll
  for (int mf = 0; mf < 4; ++mf)
#pragma unroll
    for (int nf = 0; nf < 4; ++nf) acc[mf][nf] = (f32x4){0.f, 0.f, 0.f, 0.f};

  auto stage_x = [&](int kc) {
    for (int idx = tid; idx < XR * XC * 8; idx += 512) {
      int ki4 = idx & 7, cell = idx >> 3;
      int r = cell / XC, c = cell - r * XC;
      int gr = h0 - 1 + r, gc = c - 1;
      float4 v = make_float4(0.f, 0.f, 0.f, 0.f);
      if (gr >= 0 && gr < 32 && gc >= 0 && gc < 32)
        v = *(const float4*)(xin + (((size_t)b * 32 + gr) * 32 + gc) * 256 + kc * 32 + ki4 * 4);
      float sc = rs_lds[cell];
      float x0 = v.x * sc, x1 = v.y * sc, x2 = v.z * sc, x3 = v.w * sc;
      unsigned int h0b = f2bf(x0), h1b = f2bf(x1), h2b = f2bf(x2), h3b = f2bf(x3);
      unsigned int l0b = f2bf(x0 - __uint_as_float(h0b << 16));
      unsigned int l1b = f2bf(x1 - __uint_as_float(h1b << 16));
      unsigned int l2b = f2bf(x2 - __uint_as_float(h2b << 16));
      unsigned int l3b = f2bf(x3 - __uint_as_float(h3b << 16));
      uint2 hw = make_uint2(h0b | (h1b << 16), h2b | (h3b << 16));
      uint2 lw2 = make_uint2(l0b | (l1b << 16), l2b | (l3b << 16));
      *(uint2*)(xs_h + cell * KP + ki4 * 4) = hw;
      *(uint2*)(xs_l + cell * KP + ki4 * 4) = lw2;
    }
  };

  // B chunk helpers: 1024 16B-chunks per tile-half-pair (2h x 128co x 4j);
  // thread handles chunks tid and tid+512.
  int c0h = tid >> 9, c0rem = tid & 511;
  int c0co = c0rem >> 2, c0j = c0rem & 3;
  int c1h = (tid + 512) >> 9, c1rem = (tid + 512) & 511;
  int c1co = c1rem >> 2, c1j = c1rem & 3;
  size_t g0 = (size_t)(nt * 128 + c0co) * 32 + c0j * 8;
  size_t g1 = (size_t)(nt * 128 + c1co) * 32 + c1j * 8;
  int d0 = c0co * KP + c0j * 8;
  int d1 = c1co * KP + c1j * 8;

  auto load_B = [&](int tile, uint4& u0, uint4& u1) {
    size_t tb = ((size_t)b * 72 + tile) * 8192;
    const unsigned short* s0 = (c0h ? Wc_l : Wc_h) + tb + g0;
    const unsigned short* s1 = (c1h ? Wc_l : Wc_h) + tb + g1;
    u0 = *(const uint4*)s0;
    u1 = *(const uint4*)s1;
  };
  auto write_B = [&](int buf, uint4 u0, uint4 u1) {
    *(uint4*)(&Bs[buf][c0h][d0]) = u0;
    *(uint4*)(&Bs[buf][c1h][d1]) = u1;
  };

  {
    uint4 u0, u1;
    load_B(0, u0, u1);
    write_B(0, u0, u1);
  }
  __syncthreads();  // rs_lds + Bs[0] ready

  int cur = 0;
  for (int kc = 0; kc < 8; ++kc) {
    stage_x(kc);
    __syncthreads();
    for (int tap = 0; tap < 9; ++tap) {
      int ntap = tap + 1, nkc = kc;
      if (ntap == 9) { ntap = 0; nkc = kc + 1; }
      bool pf = (nkc < 8);
      uint4 u0, u1;
      if (pf) load_B(ntap * 8 + nkc, u0, u1);

      int dy = (tap >= 6) ? 2 : ((tap >= 3) ? 1 : 0);
      int dx = tap - dy * 3;
      int aoff[4];
#pragma unroll
      for (int mf = 0; mf < 4; ++mf)
        aoff[mf] = ((prow[mf] + dy) * XC + pcb[mf] + l15 + dx) * KP + kl * 8;

      bf16x8 afh[4], bfh[4], bfl[4];
#pragma unroll
      for (int mf = 0; mf < 4; ++mf) afh[mf] = *(const bf16x8*)(xs_h + aoff[mf]);
#pragma unroll
      for (int nf = 0; nf < 4; ++nf) bfh[nf] = *(const bf16x8*)(&Bs[cur][0][boff[nf]]);
#pragma unroll
      for (int mf = 0; mf < 4; ++mf)
#pragma unroll
        for (int nf = 0; nf < 4; ++nf)
          acc[mf][nf] = __builtin_amdgcn_mfma_f32_16x16x32_bf16(afh[mf], bfh[nf], acc[mf][nf], 0, 0, 0);
#pragma unroll
      for (int nf = 0; nf < 4; ++nf) bfl[nf] = *(const bf16x8*)(&Bs[cur][1][boff[nf]]);
#pragma unroll
      for (int mf = 0; mf < 4; ++mf)
#pragma unroll
        for (int nf = 0; nf < 4; ++nf)
          acc[mf][nf] = __builtin_amdgcn_mfma_f32_16x16x32_bf16(afh[mf], bfl[nf], acc[mf][nf], 0, 0, 0);
      bf16x8 afl[4];
#pragma unroll
      for (int mf = 0; mf < 4; ++mf) afl[mf] = *(const bf16x8*)(xs_l + aoff[mf]);
#pragma unroll
      for (int mf = 0; mf < 4; ++mf)
#pragma unroll
        for (int nf = 0; nf < 4; ++nf)
          acc[mf][nf] = __builtin_amdgcn_mfma_f32_16x16x32_bf16(afl[mf], bfh[nf], acc[mf][nf], 0, 0, 0);

      if (pf) write_B(cur ^ 1, u0, u1);
      __syncthreads();
      cur ^= 1;
    }
  }

#pragma unroll
  for (int mf = 0; mf < 4; ++mf) {
    size_t rowbase = ((size_t)b * 32 + h0 + prow[mf]) * 32;
#pragma unroll
    for (int nf = 0; nf < 4; ++nf) {
      int co = nt * 128 + wn * 64 + nf * 16 + l15;
#pragma unroll
      for (int r = 0; r < 4; ++r) {
        int col = pcb[mf] + kl * 4 + r;
        out[(rowbase + col) * 256 + co] = acc[mf][nf][r] + bias[nf];
      }
    }
  }
}

extern "C" void kernel_launch(void* const* d_in, const int* in_sizes, int n_in,
                              void* d_out, int out_size, void* d_ws, size_t ws_size,
                              hipStream_t stream) {
  const float* x_in  = (const float*)d_in[0];
  const float* q     = (const float*)d_in[1];
  const float* Wk    = (const float*)d_in[2];
  const float* Wv    = (const float*)d_in[3];
  const float* Wmlp  = (const float*)d_in[4];
  const float* alpha = (const float*)d_in[5];
  const float* We    = (const float*)d_in[6];
  const float* be    = (const float*)d_in[7];
  float* out = (float*)d_out;
  float* ws = (float*)d_ws;

  float* qk       = ws;                 // 512
  float* attn     = qk + 512;           // 65536
  float* rowscale = attn + 65536;       // 32768
  float* xa_part  = rowscale + 32768;   // 262144
  float* allowed  = xa_part + 262144;   // 128
  float* selW     = allowed + 128;      // 64
  int*   selE     = (int*)(selW + 64);  // 64
  float* xbuf     = selW + 128;         // 8388608 floats
  unsigned short* Wc_h = (unsigned short*)(xbuf + 8388608);  // 18,874,368 ushorts
  unsigned short* Wc_l = Wc_h + (size_t)32 * 72 * 8192;      // 18,874,368 ushorts

  qk_kernel<<<2, 256, 0, stream>>>(Wk, q, qk);

  const float* step_in[3] = {x_in, out, xbuf};
  float* step_out[3] = {out, xbuf, out};

  for (int t = 0; t < 3; ++t) {
    const float* xc = step_in[t];
    scores_kernel<<<8192, 256, 0, stream>>>(xc, qk, attn);
    softmax_rs_kernel<<<32, 256, 0, stream>>>(attn, alpha, rowscale);
    xa_part_kernel<<<dim3(16, 32), 256, 0, stream>>>(xc, attn, xa_part);
    route_kernel<<<32, 256, 0, stream>>>(xa_part, Wv, Wmlp, allowed, selE, selW, t);
    combine_w_kernel<<<dim3(72, 32), 256, 0, stream>>>(We, selE, selW, Wc_h, Wc_l);
    conv_kernel<<<256, 512, 0, stream>>>(xc, rowscale, Wc_h, Wc_l, be, selE, selW, step_out[t]);
  }
}

// Round 7
// 461.274 us; speedup vs baseline: 1.2328x; 1.0820x over previous
//
#include <hip/hip_runtime.h>

typedef __attribute__((ext_vector_type(8))) short bf16x8;
typedef __attribute__((ext_vector_type(4))) float f32x4;

#define CC 256
#define SS 1024
#define KK 4
#define XR 6
#define XC 34
#define NCELL (XR * XC)  // 204

__device__ __forceinline__ unsigned int f2bf(float v) {
  unsigned int u = __float_as_uint(v);
  return (u + 0x7FFFu + ((u >> 16) & 1u)) >> 16;
}

__device__ __forceinline__ void gll16(const void* g, void* l) {
  __builtin_amdgcn_global_load_lds((const __attribute__((address_space(1))) void*)g,
                                   (__attribute__((address_space(3))) void*)l, 16, 0, 0);
}

#define S_VMCNT0 asm volatile("s_waitcnt vmcnt(0)" ::: "memory")
#define S_LGKM0 asm volatile("s_waitcnt lgkmcnt(0)" ::: "memory")

// qk[c][n] = sum_d Wk[c, n*64+d] * q[n, d]
__global__ void qk_kernel(const float* __restrict__ Wk, const float* __restrict__ q,
                          float* __restrict__ qk) {
  int t = blockIdx.x * blockDim.x + threadIdx.x;
  if (t >= CC * 2) return;
  int c = t >> 1, n = t & 1;
  float s = 0.f;
  for (int d = 0; d < 64; ++d) s += Wk[c * 128 + n * 64 + d] * q[n * 64 + d];
  qk[c * 2 + n] = s;
}

// scores[b][n][s] = (x[b,s,:] . qk[:,n]) / 8   (one wave per pixel)
__global__ void scores_kernel(const float* __restrict__ x, const float* __restrict__ qk,
                              float* __restrict__ attn) {
  int wave = threadIdx.x >> 6, lane = threadIdx.x & 63;
  int pix = blockIdx.x * 4 + wave;
  int b = pix >> 10, s = pix & 1023;
  const float4 xv = *(const float4*)(x + (size_t)pix * CC + lane * 4);
  float d0 = 0.f, d1 = 0.f;
  const float* xp = (const float*)&xv;
#pragma unroll
  for (int j = 0; j < 4; ++j) {
    float xc = xp[j];
    d0 += xc * qk[(lane * 4 + j) * 2 + 0];
    d1 += xc * qk[(lane * 4 + j) * 2 + 1];
  }
#pragma unroll
  for (int m = 32; m >= 1; m >>= 1) {
    d0 += __shfl_xor(d0, m, 64);
    d1 += __shfl_xor(d1, m, 64);
  }
  if (lane == 0) {
    attn[((size_t)b * 2 + 0) * SS + s] = d0 * 0.125f;
    attn[((size_t)b * 2 + 1) * SS + s] = d1 * 0.125f;
  }
}

// block per batch: softmax both heads in-place + rowscale
__global__ void softmax_rs_kernel(float* __restrict__ attn, const float* __restrict__ alpha,
                                  float* __restrict__ rowscale) {
  __shared__ float red0[4], red1[4];
  int b = blockIdx.x, tid = threadIdx.x;
  float* p0 = attn + (size_t)b * 2048;
  float* p1 = p0 + 1024;
  float4 v0 = *(float4*)(p0 + tid * 4);
  float4 v1 = *(float4*)(p1 + tid * 4);
  float m0 = fmaxf(fmaxf(v0.x, v0.y), fmaxf(v0.z, v0.w));
  float m1 = fmaxf(fmaxf(v1.x, v1.y), fmaxf(v1.z, v1.w));
#pragma unroll
  for (int sh = 32; sh >= 1; sh >>= 1) {
    m0 = fmaxf(m0, __shfl_xor(m0, sh, 64));
    m1 = fmaxf(m1, __shfl_xor(m1, sh, 64));
  }
  if ((tid & 63) == 0) { red0[tid >> 6] = m0; red1[tid >> 6] = m1; }
  __syncthreads();
  m0 = fmaxf(fmaxf(red0[0], red0[1]), fmaxf(red0[2], red0[3]));
  m1 = fmaxf(fmaxf(red1[0], red1[1]), fmaxf(red1[2], red1[3]));
  float4 e0, e1;
  e0.x = expf(v0.x - m0); e0.y = expf(v0.y - m0); e0.z = expf(v0.z - m0); e0.w = expf(v0.w - m0);
  e1.x = expf(v1.x - m1); e1.y = expf(v1.y - m1); e1.z = expf(v1.z - m1); e1.w = expf(v1.w - m1);
  float s0 = e0.x + e0.y + e0.z + e0.w;
  float s1 = e1.x + e1.y + e1.z + e1.w;
#pragma unroll
  for (int sh = 32; sh >= 1; sh >>= 1) {
    s0 += __shfl_xor(s0, sh, 64);
    s1 += __shfl_xor(s1, sh, 64);
  }
  __syncthreads();
  if ((tid & 63) == 0) { red0[tid >> 6] = s0; red1[tid >> 6] = s1; }
  __syncthreads();
  s0 = red0[0] + red0[1] + red0[2] + red0[3];
  s1 = red1[0] + red1[1] + red1[2] + red1[3];
  float i0 = 1.f / s0, i1 = 1.f / s1;
  e0.x *= i0; e0.y *= i0; e0.z *= i0; e0.w *= i0;
  e1.x *= i1; e1.y *= i1; e1.z *= i1; e1.w *= i1;
  *(float4*)(p0 + tid * 4) = e0;
  *(float4*)(p1 + tid * 4) = e1;
  float al = alpha[0];
  float a = (al > 20.f) ? al : log1pf(expf(al));
  float k = 0.5f * 1024.f * a;
  float4 rs;
  rs.x = 1.f + (e0.x + e1.x) * k;
  rs.y = 1.f + (e0.y + e1.y) * k;
  rs.z = 1.f + (e0.z + e1.z) * k;
  rs.w = 1.f + (e0.w + e1.w) * k;
  *(float4*)(rowscale + (size_t)b * 1024 + tid * 4) = rs;
}

// partial xa over 64-s chunks: xa_part[b][ch][n][c]
__global__ void xa_part_kernel(const float* __restrict__ x, const float* __restrict__ attn,
                               float* __restrict__ xa_part) {
  int ch = blockIdx.x, b = blockIdx.y, c = threadIdx.x;
  int s0 = ch * 64;
  const float* a0 = attn + (size_t)b * 2048 + s0;
  const float* a1 = a0 + 1024;
  const float* xb = x + ((size_t)b * 1024 + s0) * CC + c;
  float acc0 = 0.f, acc1 = 0.f;
  for (int i = 0; i < 64; ++i) {
    float xv = xb[(size_t)i * CC];
    acc0 += a0[i] * xv;
    acc1 += a1[i] * xv;
  }
  float* o = xa_part + ((size_t)b * 16 + ch) * 512;
  o[c] = acc0;
  o[256 + c] = acc1;
}

// reduce xa_part -> pooled -> logits -> top-2 routing
__global__ void route_kernel(const float* __restrict__ xa_part, const float* __restrict__ Wv,
                             const float* __restrict__ Wmlp, float* __restrict__ allowed,
                             int* __restrict__ selE, float* __restrict__ selW, int step) {
  __shared__ float xs[512];
  __shared__ float pooled[128];
  __shared__ float lg[4];
  int b = blockIdx.x, tid = threadIdx.x;
#pragma unroll
  for (int i = 0; i < 2; ++i) {
    int id = tid + i * 256;
    float s = 0.f;
    for (int ch = 0; ch < 16; ++ch) s += xa_part[((size_t)b * 16 + ch) * 512 + id];
    xs[id] = s;
  }
  __syncthreads();
  if (tid < 128) {
    int n = tid >> 6;
    float s = 0.f;
    const float* xr = xs + n * 256;
    for (int c = 0; c < 256; ++c) s += xr[c] * Wv[(size_t)c * 128 + tid];
    pooled[tid] = s;
  }
  __syncthreads();
  if (tid < 4) {
    float s = 0.f;
    for (int d = 0; d < 128; ++d) s += pooled[d] * Wmlp[d * 4 + tid];
    lg[tid] = s;
  }
  __syncthreads();
  if (tid == 0) {
    float al[KK];
    if (step == 0) { for (int k = 0; k < KK; ++k) al[k] = 1.f; }
    else           { for (int k = 0; k < KK; ++k) al[k] = allowed[b * KK + k]; }
    float ml[KK];
    for (int k = 0; k < KK; ++k)
      ml[k] = (al[k] > 0.5f) ? lg[k] * (1.f / 1.5f) : (-1e9f) * (1.f / 1.5f);
    float m = ml[0];
    for (int k = 1; k < KK; ++k) m = fmaxf(m, ml[k]);
    float e[KK], ssum = 0.f;
    for (int k = 0; k < KK; ++k) { e[k] = expf(ml[k] - m); ssum += e[k]; }
    float w[KK];
    for (int k = 0; k < KK; ++k) w[k] = e[k] / ssum;
    int i0 = 0;
    for (int k = 1; k < KK; ++k) if (w[k] > w[i0]) i0 = k;
    int i1 = -1;
    for (int k = 0; k < KK; ++k) {
      if (k == i0) continue;
      if (i1 < 0 || w[k] > w[i1]) i1 = k;
    }
    float denom = w[i0] + w[i1] + 1e-9f;
    selE[b * 2 + 0] = i0;
    selE[b * 2 + 1] = i1;
    selW[b * 2 + 0] = w[i0] / denom;
    selW[b * 2 + 1] = w[i1] / denom;
    if (i0 != KK - 1) al[i0] = fminf(fmaxf(al[i0] - 1.f, 0.f), 1.f);
    al[KK - 1] = fmaxf(al[KK - 1], 1.f);
    for (int k = 0; k < KK; ++k) allowed[b * KK + k] = al[k];
  }
}

// Per-batch combined expert weights (exact f32 combine), split to bf16 hi/lo,
// transposed packed layout: Wc_{h,l}[(b*72 + tile)*8192 + co*32 + ki]
__global__ void combine_w_kernel(const float* __restrict__ We,
                                 const int* __restrict__ selE, const float* __restrict__ selW,
                                 unsigned short* __restrict__ Wc_h,
                                 unsigned short* __restrict__ Wc_l) {
  int tile = blockIdx.x;  // 0..71 = tap*8+kc
  int b = blockIdx.y;
  int tap = tile >> 3, kc = tile & 7;
  int co = threadIdx.x;
  int e0 = selE[b * 2], e1 = selE[b * 2 + 1];
  float w0 = selW[b * 2], w1 = selW[b * 2 + 1];
  __shared__ float ts[32][257];
  const float* s0 = We + (size_t)(e0 * 9 + tap) * 65536 + (size_t)(kc * 32) * 256 + co;
  const float* s1 = We + (size_t)(e1 * 9 + tap) * 65536 + (size_t)(kc * 32) * 256 + co;
  for (int ci = 0; ci < 32; ++ci)
    ts[ci][co] = w0 * s0[(size_t)ci * 256] + w1 * s1[(size_t)ci * 256];
  __syncthreads();
  __align__(16) unsigned short hh[32];
  __align__(16) unsigned short ll[32];
#pragma unroll
  for (int ki = 0; ki < 32; ++ki) {
    float v = ts[ki][co];
    unsigned int h = f2bf(v);
    unsigned int l = f2bf(v - __uint_as_float(h << 16));
    hh[ki] = (unsigned short)h;
    ll[ki] = (unsigned short)l;
  }
  size_t base = ((size_t)b * 72 + tile) * 8192 + (size_t)co * 32;
#pragma unroll
  for (int j = 0; j < 4; ++j) {
    *(uint4*)(Wc_h + base + j * 8) = *(const uint4*)(hh + j * 8);
    *(uint4*)(Wc_l + base + j * 8) = *(const uint4*)(ll + j * 8);
  }
}

// MFMA implicit-GEMM conv. Block = 256 thr (4 waves, 2m x 2n), tile
// M=128 pixels (4 image rows + halo), N=128 cos; wave tile 64x64.
// x (hi|lo) in XOR-swizzled LDS (128B/cell rows); B streamed global->LDS via
// global_load_lds with pre-swizzled per-lane source, double-buffered.
// Raw s_barrier with lgkm-only / early-drained vmcnt. setprio around MFMA.
__global__ __launch_bounds__(256, 2) void conv_kernel(
    const float* __restrict__ xin, const float* __restrict__ rowscale,
    const unsigned short* __restrict__ Wc_h, const unsigned short* __restrict__ Wc_l,
    const float* __restrict__ be,
    const int* __restrict__ selE, const float* __restrict__ selW,
    float* __restrict__ out) {
  __shared__ __align__(16) unsigned char xsB[NCELL * 128];   // 26112 B
  __shared__ __align__(16) unsigned char BsB[2][16384];      // 32768 B

  int bid = blockIdx.x;
  int xcd = bid & 7, t2 = bid >> 3;
  int mt = t2 & 7, gs = t2 >> 3;
  int g = gs * 8 + xcd;           // (b,nt) group; its 8 mt-blocks share one XCD
  int b = g >> 1, nt = g & 1;
  int h0 = mt * 4;
  int tid = threadIdx.x;
  int lane = tid & 63, wid = tid >> 6;
  int wm = wid >> 1, wn = wid & 1;
  int l15 = lane & 15, kl = lane >> 4;

  int e0 = selE[b * 2], e1 = selE[b * 2 + 1];
  float w0 = selW[b * 2], w1 = selW[b * 2 + 1];

  // A-frag cell bases per mf (pixel p = wm*64+mf*16+l15; never crosses a row of 32)
  int cellb[4];
#pragma unroll
  for (int mf = 0; mf < 4; ++mf) {
    int p0 = wm * 64 + mf * 16;
    cellb[mf] = (p0 >> 5) * XC + (p0 & 31) + l15;
  }
  // B-frag hi byte offsets (tap-invariant)
  int bbyte[4];
#pragma unroll
  for (int nf = 0; nf < 4; ++nf) {
    int co = wn * 64 + nf * 16 + l15;
    bbyte[nf] = (co * 128 + kl * 16) ^ ((co & 7) << 4);
  }
  // global_load_lds lane mapping: dest D = wid*4096 + j*1024 + lane*16 (linear);
  // logical slot u = (lane&7) ^ (lane>>3); source = half-table[u>>2], q = u&3.
  int uu = (lane & 7) ^ (lane >> 3);
  int qy = uu & 3;
  const unsigned short* srcSel = ((uu >> 2) ? Wc_l : Wc_h) + (size_t)b * 72 * 8192;
  int elemoff[4];
#pragma unroll
  for (int j = 0; j < 4; ++j) {
    int co = wid * 32 + j * 8 + (lane >> 3);
    elemoff[j] = (nt * 128 + co) * 32 + qy * 8;
  }

  float bias[4];
#pragma unroll
  for (int nf = 0; nf < 4; ++nf) {
    int con = nt * 128 + wn * 64 + nf * 16 + l15;
    bias[nf] = w0 * be[e0 * 256 + con] + w1 * be[e1 * 256 + con];
  }

  f32x4 acc[4][4];
#pragma unroll
  for (int mf = 0; mf < 4; ++mf)
#pragma unroll
    for (int nf = 0; nf < 4; ++nf) acc[mf][nf] = (f32x4){0.f, 0.f, 0.f, 0.f};

  // Stage x (hi|lo split, x_mod fused) into swizzled LDS for K-chunk kcc.
  auto stage_x = [&](int kcc) {
    for (int idx = tid; idx < NCELL * 2; idx += 256) {
      int cell = idx >> 1, hk = idx & 1;
      int r = cell / XC, c = cell - r * XC;
      int gr = h0 - 1 + r, gc = c - 1;
      uint4 hA = make_uint4(0, 0, 0, 0), hB = make_uint4(0, 0, 0, 0);
      uint4 lA = make_uint4(0, 0, 0, 0), lB = make_uint4(0, 0, 0, 0);
      if (gr >= 0 && gr < 32 && gc >= 0 && gc < 32) {
        const float* src = xin + (((size_t)b * 32 + gr) * 32 + gc) * 256 + kcc * 32 + hk * 16;
        float sc = rowscale[(size_t)b * 1024 + gr * 32 + gc];
        float xv[16];
        *(float4*)(xv + 0) = *(const float4*)(src + 0);
        *(float4*)(xv + 4) = *(const float4*)(src + 4);
        *(float4*)(xv + 8) = *(const float4*)(src + 8);
        *(float4*)(xv + 12) = *(const float4*)(src + 12);
        unsigned int hw[8], lw[8];
#pragma unroll
        for (int e2 = 0; e2 < 8; ++e2) {
          float c0 = xv[e2 * 2] * sc, c1 = xv[e2 * 2 + 1] * sc;
          unsigned int hb0 = f2bf(c0);
          unsigned int lb0 = f2bf(c0 - __uint_as_float(hb0 << 16));
          unsigned int hb1 = f2bf(c1);
          unsigned int lb1 = f2bf(c1 - __uint_as_float(hb1 << 16));
          hw[e2] = hb0 | (hb1 << 16);
          lw[e2] = lb0 | (lb1 << 16);
        }
        hA = make_uint4(hw[0], hw[1], hw[2], hw[3]);
        hB = make_uint4(hw[4], hw[5], hw[6], hw[7]);
        lA = make_uint4(lw[0], lw[1], lw[2], lw[3]);
        lB = make_uint4(lw[4], lw[5], lw[6], lw[7]);
      }
      int sx = (cell & 7) << 4;
      int b0 = (cell * 128 + (2 * hk + 0) * 16) ^ sx;
      int b1 = (cell * 128 + (2 * hk + 1) * 16) ^ sx;
      *(uint4*)(xsB + b0) = hA;
      *(uint4*)(xsB + b1) = hB;
      *(uint4*)(xsB + (b0 ^ 64)) = lA;
      *(uint4*)(xsB + (b1 ^ 64)) = lB;
    }
  };

  auto issue_B = [&](int tile, int buf) {
    const unsigned short* sp = srcSel + (size_t)tile * 8192;
    char* lbase = (char*)BsB[buf] + wid * 4096;
#pragma unroll
    for (int j = 0; j < 4; ++j) gll16(sp + elemoff[j], lbase + j * 1024);
    __builtin_amdgcn_sched_barrier(0);
  };

  // ---- prologue ----
  issue_B(0, 0);
  stage_x(0);
  S_VMCNT0;
  S_LGKM0;
  __builtin_amdgcn_sched_barrier(0);
  __builtin_amdgcn_s_barrier();

  int tap = 0, kc = 0;
  for (int tk = 0; tk < 72; ++tk) {
    int cur = tk & 1;
    int ntap = tap + 1, nkc = kc;
    if (ntap == 9) { ntap = 0; nkc = kc + 1; }
    if (tk < 71) issue_B(ntap * 8 + nkc, cur ^ 1);

    int dy = (tap >= 6) ? 2 : ((tap >= 3) ? 1 : 0);
    int dx = tap - dy * 3;
    int dcell = dy * XC + dx;
    const unsigned char* bp = (const unsigned char*)BsB[cur];

    bf16x8 af[4], bfh[4], bfl[4];
    int abyte[4];
#pragma unroll
    for (int mf = 0; mf < 4; ++mf) {
      int cell = cellb[mf] + dcell;
      abyte[mf] = (cell * 128 + kl * 16) ^ ((cell & 7) << 4);
      af[mf] = *(const bf16x8*)(xsB + abyte[mf]);
    }
#pragma unroll
    for (int nf = 0; nf < 4; ++nf) bfh[nf] = *(const bf16x8*)(bp + bbyte[nf]);
    __builtin_amdgcn_s_setprio(1);
#pragma unroll
    for (int mf = 0; mf < 4; ++mf)
#pragma unroll
      for (int nf = 0; nf < 4; ++nf)
        acc[mf][nf] = __builtin_amdgcn_mfma_f32_16x16x32_bf16(af[mf], bfh[nf], acc[mf][nf], 0, 0, 0);
    __builtin_amdgcn_s_setprio(0);
#pragma unroll
    for (int nf = 0; nf < 4; ++nf) bfl[nf] = *(const bf16x8*)(bp + (bbyte[nf] ^ 64));
    __builtin_amdgcn_s_setprio(1);
#pragma unroll
    for (int mf = 0; mf < 4; ++mf)
#pragma unroll
      for (int nf = 0; nf < 4; ++nf)
        acc[mf][nf] = __builtin_amdgcn_mfma_f32_16x16x32_bf16(af[mf], bfl[nf], acc[mf][nf], 0, 0, 0);
    __builtin_amdgcn_s_setprio(0);
#pragma unroll
    for (int mf = 0; mf < 4; ++mf) af[mf] = *(const bf16x8*)(xsB + (abyte[mf] ^ 64));
    __builtin_amdgcn_s_setprio(1);
#pragma unroll
    for (int mf = 0; mf < 4; ++mf)
#pragma unroll
      for (int nf = 0; nf < 4; ++nf)
        acc[mf][nf] = __builtin_amdgcn_mfma_f32_16x16x32_bf16(af[mf], bfh[nf], acc[mf][nf], 0, 0, 0);
    __builtin_amdgcn_s_setprio(0);

    if (tk < 71) {
      S_VMCNT0;  // gll for next tap (issued ~1800 cyc ago) -> cheap
      __builtin_amdgcn_sched_barrier(0);
      __builtin_amdgcn_s_barrier();
      if (ntap == 0) {
        stage_x(nkc);
        S_LGKM0;
        __builtin_amdgcn_sched_barrier(0);
        __builtin_amdgcn_s_barrier();
      }
    }
    tap = ntap;
    kc = nkc;
  }

#pragma unroll
  for (int mf = 0; mf < 4; ++mf) {
    int p0 = wm * 64 + mf * 16;
    int pr = p0 >> 5, pc = p0 & 31;
    size_t rowbase = ((size_t)b * 32 + h0 + pr) * 32;
#pragma unroll
    for (int nf = 0; nf < 4; ++nf) {
      int co = nt * 128 + wn * 64 + nf * 16 + l15;
#pragma unroll
      for (int rr = 0; rr < 4; ++rr) {
        int col = pc + kl * 4 + rr;
        out[(rowbase + col) * 256 + co] = acc[mf][nf][rr] + bias[nf];
      }
    }
  }
}

extern "C" void kernel_launch(void* const* d_in, const int* in_sizes, int n_in,
                              void* d_out, int out_size, void* d_ws, size_t ws_size,
                              hipStream_t stream) {
  const float* x_in  = (const float*)d_in[0];
  const float* q     = (const float*)d_in[1];
  const float* Wk    = (const float*)d_in[2];
  const float* Wv    = (const float*)d_in[3];
  const float* Wmlp  = (const float*)d_in[4];
  const float* alpha = (const float*)d_in[5];
  const float* We    = (const float*)d_in[6];
  const float* be    = (const float*)d_in[7];
  float* out = (float*)d_out;
  float* ws = (float*)d_ws;

  float* qk       = ws;                 // 512
  float* attn     = qk + 512;           // 65536
  float* rowscale = attn + 65536;       // 32768
  float* xa_part  = rowscale + 32768;   // 262144
  float* allowed  = xa_part + 262144;   // 128
  float* selW     = allowed + 128;      // 64
  int*   selE     = (int*)(selW + 64);  // 64
  float* xbuf     = selW + 128;         // 8388608 floats
  unsigned short* Wc_h = (unsigned short*)(xbuf + 8388608);  // 18,874,368 ushorts
  unsigned short* Wc_l = Wc_h + (size_t)32 * 72 * 8192;      // 18,874,368 ushorts

  qk_kernel<<<2, 256, 0, stream>>>(Wk, q, qk);

  const float* step_in[3] = {x_in, out, xbuf};
  float* step_out[3] = {out, xbuf, out};

  for (int t = 0; t < 3; ++t) {
    const float* xc = step_in[t];
    scores_kernel<<<8192, 256, 0, stream>>>(xc, qk, attn);
    softmax_rs_kernel<<<32, 256, 0, stream>>>(attn, alpha, rowscale);
    xa_part_kernel<<<dim3(16, 32), 256, 0, stream>>>(xc, attn, xa_part);
    route_kernel<<<32, 256, 0, stream>>>(xa_part, Wv, Wmlp, allowed, selE, selW, t);
    combine_w_kernel<<<dim3(72, 32), 256, 0, stream>>>(We, selE, selW, Wc_h, Wc_l);
    conv_kernel<<<512, 256, 0, stream>>>(xc, rowscale, Wc_h, Wc_l, be, selE, selW, step_out[t]);
  }
}